// Round 1
// baseline (205.021 us; speedup 1.0000x reference)
//
#include <hip/hip_runtime.h>
#include <stdint.h>

#define NHEADS 12
#define HDIM   64
#define NB     4
#define SQ     1024
#define DM     768
#define NROWS  (NB*SQ)      // 4096
#define NWE    (DM*DM)      // 589824
#define NXE    (NROWS*DM)   // 3145728

typedef __attribute__((ext_vector_type(8))) short short8;
typedef __attribute__((ext_vector_type(4))) float f32x4;

__device__ __forceinline__ unsigned short f2bf(float f) {
  union { float f; unsigned u; } v; v.f = f;
  return (unsigned short)((v.u + 0x7fffu + ((v.u >> 16) & 1u)) >> 16);
}

__device__ __forceinline__ void gload16(const void* g, void* l) {
  __builtin_amdgcn_global_load_lds((__attribute__((address_space(1))) void*)(void*)g,
                                   (__attribute__((address_space(3))) void*)l, 16, 0, 0);
}

// ---------------- prep: fp32 -> bf16 conversions + box centers ----------------
__global__ __launch_bounds__(256) void prep_kernel(
    const float* __restrict__ x, const float* __restrict__ Wq, const float* __restrict__ Wk,
    const float* __restrict__ Wv, const float* __restrict__ Wo, const float* __restrict__ boxes,
    unsigned short* __restrict__ xb, unsigned short* __restrict__ wcat,
    unsigned short* __restrict__ wob, float2* __restrict__ centers) {
  int i = blockIdx.x * 256 + threadIdx.x;
  if (i < NXE) { xb[i] = f2bf(x[i]); return; }
  i -= NXE;
  if (i < NWE) {
    wcat[i]           = f2bf(Wq[i]);
    wcat[NWE + i]     = f2bf(Wk[i]);
    wcat[2 * NWE + i] = f2bf(Wv[i]);
    wob[i]            = f2bf(Wo[i]);
    return;
  }
  i -= NWE;
  if (i < NROWS) {
    float4 bx = ((const float4*)boxes)[i];
    centers[i] = make_float2((bx.x + bx.z) * 0.5f, (bx.y + bx.w) * 0.5f);
  }
}

// ---------------- NT GEMM: C[M,N] = A[M,K] * B[N,K]^T  (bf16 in, fp32 acc) ----
// 128x128 tile, 4 waves (2x2 of 64x64), 16x16x32 bf16 MFMA, global_load_lds.
// EPI=0: QKV epilogue (scatter to Q[bh,s,d], K[bh,s,d], Vt[bh,d,s] bf16, +bias)
// EPI=1: fp32 out = acc + b0[n]
template <int EPI>
__global__ __launch_bounds__(256, 2) void gemm_bt(
    const unsigned short* __restrict__ A, const unsigned short* __restrict__ Bw,
    int K, int tiles_n,
    const float* __restrict__ b0, const float* __restrict__ b1, const float* __restrict__ b2,
    unsigned short* __restrict__ outQ, unsigned short* __restrict__ outK,
    unsigned short* __restrict__ outVt, float* __restrict__ outF) {
  __shared__ unsigned short lA[128 * 32];
  __shared__ unsigned short lB[128 * 32];
  const int tid = threadIdx.x, wave = tid >> 6, lane = tid & 63;
  const int tm = blockIdx.x / tiles_n, tn = blockIdx.x % tiles_n;
  const int wr = wave >> 1, wc = wave & 1;
  const int g = lane >> 4, c16 = lane & 15, kb8 = g * 8;

  f32x4 acc[4][4];
#pragma unroll
  for (int m = 0; m < 4; m++)
#pragma unroll
    for (int n = 0; n < 4; n++) acc[m][n] = (f32x4){0.f, 0.f, 0.f, 0.f};

  const unsigned short* Abase = A + (size_t)tm * 128 * K;
  const unsigned short* Bbase = Bw + (size_t)tn * 128 * K;
  // staging: 8KB tile = 8 chunks of 1KB; wave w does chunks w and w+4.
  // LDS dest is wave-uniform base + lane*16 (m104) -> linear layout.
  const int lin0 = wave * 1024 + lane * 16;
  const int row0 = lin0 >> 6, cb0 = lin0 & 63;
  const int lin1 = lin0 + 4096;
  const int row1 = lin1 >> 6, cb1 = lin1 & 63;

  for (int kt = 0; kt < K; kt += 32) {
    __syncthreads();
    gload16((const char*)(Abase + (size_t)row0 * K + kt) + cb0, (char*)lA + wave * 1024);
    gload16((const char*)(Abase + (size_t)row1 * K + kt) + cb1, (char*)lA + wave * 1024 + 4096);
    gload16((const char*)(Bbase + (size_t)row0 * K + kt) + cb0, (char*)lB + wave * 1024);
    gload16((const char*)(Bbase + (size_t)row1 * K + kt) + cb1, (char*)lB + wave * 1024 + 4096);
    __syncthreads();
    short8 a[4], b[4];
#pragma unroll
    for (int m = 0; m < 4; m++) a[m] = *(const short8*)&lA[(wr * 64 + m * 16 + c16) * 32 + kb8];
#pragma unroll
    for (int n = 0; n < 4; n++) b[n] = *(const short8*)&lB[(wc * 64 + n * 16 + c16) * 32 + kb8];
#pragma unroll
    for (int m = 0; m < 4; m++)
#pragma unroll
      for (int n = 0; n < 4; n++)
        acc[m][n] = __builtin_amdgcn_mfma_f32_16x16x32_bf16(a[m], b[n], acc[m][n], 0, 0, 0);
  }

  // C/D layout (m89): col = lane&15, row = (lane>>4)*4 + r
#pragma unroll
  for (int m = 0; m < 4; m++) {
    const int gm0 = tm * 128 + wr * 64 + m * 16 + g * 4;
    const int bb = gm0 >> 10, ss0 = gm0 & 1023;
#pragma unroll
    for (int n = 0; n < 4; n++) {
      const int gn = tn * 128 + wc * 64 + n * 16 + c16;
      if (EPI == 0) {
        const int which = gn / DM, nn = gn - which * DM;
        const int h = nn >> 6, dh = nn & 63;
        const float bias = (which == 0 ? b0 : which == 1 ? b1 : b2)[nn];
        if (which == 2) {
          ushort4 pk;
          pk.x = f2bf(acc[m][n][0] + bias);
          pk.y = f2bf(acc[m][n][1] + bias);
          pk.z = f2bf(acc[m][n][2] + bias);
          pk.w = f2bf(acc[m][n][3] + bias);
          *(ushort4*)&outVt[(((size_t)bb * NHEADS + h) * HDIM + dh) * SQ + ss0] = pk;
        } else {
          unsigned short* dst = (which == 0 ? outQ : outK) + ((size_t)bb * NHEADS + h) * SQ * HDIM;
#pragma unroll
          for (int r = 0; r < 4; r++)
            dst[(size_t)(ss0 + r) * HDIM + dh] = f2bf(acc[m][n][r] + bias);
        }
      } else {
        const float bias = b0[gn];
#pragma unroll
        for (int r = 0; r < 4; r++)
          outF[(size_t)(gm0 + r) * DM + gn] = acc[m][n][r] + bias;
      }
    }
  }
}

// ---------------- fused spatial attention (flash-style, online softmax) -------
// grid: 384 blocks = 48 bh * 8 qtiles, XCD-swizzled so each XCD owns 6 heads.
// block: 4 waves, each wave owns 32 q-rows; K/V read direct from global (L2-fit).
__global__ __launch_bounds__(256, 2) void attn_kernel(
    const unsigned short* __restrict__ Qb, const unsigned short* __restrict__ Kb,
    const unsigned short* __restrict__ Vt, const float2* __restrict__ centers,
    const float* __restrict__ sbias, unsigned short* __restrict__ attb) {
  __shared__ unsigned short plds[4][32 * 48];  // per-wave P tile [32 rows][32+pad]
  const int tid = threadIdx.x, wave = tid >> 6, lane = tid & 63;
  const int g = lane >> 4, c16 = lane & 15, kb8 = g * 8;
  // bijective swizzle: all 8 q-tiles of a head land on the same XCD residue
  const int bid = blockIdx.x;
  const int xcd = bid & 7, li = bid >> 3;       // li in 0..47
  const int bh = xcd * 6 + (li >> 3);
  const int qt = li & 7;
  const int b = bh / NHEADS, h = bh - b * NHEADS;
  const float sb = sbias[h];

  const unsigned short* Qh = Qb + (size_t)bh * SQ * HDIM;
  const unsigned short* Kh = Kb + (size_t)bh * SQ * HDIM;
  const unsigned short* Vh = Vt + (size_t)bh * HDIM * SQ;
  const float2* cent = centers + b * SQ;

  const int q0 = qt * 128 + wave * 32;
  short8 qf[2][2];
#pragma unroll
  for (int m = 0; m < 2; m++)
#pragma unroll
    for (int kc = 0; kc < 2; kc++)
      qf[m][kc] = *(const short8*)&Qh[(size_t)(q0 + m * 16 + c16) * HDIM + kc * 32 + kb8];

  float cqx[2][4], cqy[2][4];
#pragma unroll
  for (int m = 0; m < 2; m++)
#pragma unroll
    for (int r = 0; r < 4; r++) {
      float2 cc = cent[q0 + m * 16 + g * 4 + r];
      cqx[m][r] = cc.x; cqy[m][r] = cc.y;
    }

  float mrow[2][4], lrow[2][4];
  f32x4 oacc[2][4];
#pragma unroll
  for (int m = 0; m < 2; m++) {
#pragma unroll
    for (int r = 0; r < 4; r++) { mrow[m][r] = -1e30f; lrow[m][r] = 0.f; }
#pragma unroll
    for (int c4 = 0; c4 < 4; c4++) oacc[m][c4] = (f32x4){0.f, 0.f, 0.f, 0.f};
  }

  for (int tb = 0; tb < SQ; tb += 32) {
    // --- QK^T: 32 q-rows x 32 tokens, scores in C layout ---
    f32x4 sv[2][2];
    short8 kf[2][2];
#pragma unroll
    for (int cc = 0; cc < 2; cc++) {
      kf[cc][0] = *(const short8*)&Kh[(size_t)(tb + cc * 16 + c16) * HDIM + kb8];
      kf[cc][1] = *(const short8*)&Kh[(size_t)(tb + cc * 16 + c16) * HDIM + 32 + kb8];
    }
#pragma unroll
    for (int cc = 0; cc < 2; cc++)
#pragma unroll
      for (int m = 0; m < 2; m++) {
        f32x4 s = (f32x4){0.f, 0.f, 0.f, 0.f};
        s = __builtin_amdgcn_mfma_f32_16x16x32_bf16(qf[m][0], kf[cc][0], s, 0, 0, 0);
        s = __builtin_amdgcn_mfma_f32_16x16x32_bf16(qf[m][1], kf[cc][1], s, 0, 0, 0);
        sv[m][cc] = s;
      }
    // --- spatial bias: -dist(center_q, center_t) * sb, scale QK by 1/8 ---
    float ctx[2], cty[2];
#pragma unroll
    for (int cc = 0; cc < 2; cc++) {
      float2 ct = cent[tb + cc * 16 + c16];
      ctx[cc] = ct.x; cty[cc] = ct.y;
    }
    float pv[2][2][4];
#pragma unroll
    for (int m = 0; m < 2; m++)
#pragma unroll
      for (int cc = 0; cc < 2; cc++)
#pragma unroll
        for (int r = 0; r < 4; r++) {
          float dx = cqx[m][r] - ctx[cc], dy = cqy[m][r] - cty[cc];
          pv[m][cc][r] = sv[m][cc][r] * 0.125f - sqrtf(dx * dx + dy * dy) * sb;
        }
    // --- online softmax update (rows live in 16-lane groups) ---
    float scl[2][4];
#pragma unroll
    for (int m = 0; m < 2; m++)
#pragma unroll
      for (int r = 0; r < 4; r++) {
        float vmax = fmaxf(pv[m][0][r], pv[m][1][r]);
#pragma unroll
        for (int msk = 1; msk < 16; msk <<= 1) vmax = fmaxf(vmax, __shfl_xor(vmax, msk));
        float mn = fmaxf(mrow[m][r], vmax);
        float sc = __expf(mrow[m][r] - mn);
        float p0 = __expf(pv[m][0][r] - mn);
        float p1 = __expf(pv[m][1][r] - mn);
        pv[m][0][r] = p0; pv[m][1][r] = p1;
        float ps = p0 + p1;
#pragma unroll
        for (int msk = 1; msk < 16; msk <<= 1) ps += __shfl_xor(ps, msk);
        lrow[m][r] = lrow[m][r] * sc + ps;
        mrow[m][r] = mn;
        scl[m][r] = sc;
      }
#pragma unroll
    for (int m = 0; m < 2; m++)
#pragma unroll
      for (int c4 = 0; c4 < 4; c4++)
#pragma unroll
        for (int r = 0; r < 4; r++) oacc[m][c4][r] *= scl[m][r];
    // --- P -> LDS (C layout -> A-frag layout), then PV MFMA ---
#pragma unroll
    for (int m = 0; m < 2; m++)
#pragma unroll
      for (int cc = 0; cc < 2; cc++)
#pragma unroll
        for (int r = 0; r < 4; r++)
          plds[wave][(m * 16 + g * 4 + r) * 48 + cc * 16 + c16] = f2bf(pv[m][cc][r]);
    short8 vf[4];
#pragma unroll
    for (int c4 = 0; c4 < 4; c4++)
      vf[c4] = *(const short8*)&Vh[(size_t)(c4 * 16 + c16) * SQ + tb + kb8];
#pragma unroll
    for (int m = 0; m < 2; m++) {
      short8 pa = *(const short8*)&plds[wave][(m * 16 + c16) * 48 + kb8];
#pragma unroll
      for (int c4 = 0; c4 < 4; c4++)
        oacc[m][c4] = __builtin_amdgcn_mfma_f32_16x16x32_bf16(pa, vf[c4], oacc[m][c4], 0, 0, 0);
    }
  }
  // --- epilogue: O/l -> attended [b*S+s][h*64+dh] bf16 ---
#pragma unroll
  for (int m = 0; m < 2; m++)
#pragma unroll
    for (int c4 = 0; c4 < 4; c4++)
#pragma unroll
      for (int r = 0; r < 4; r++) {
        const int qs = q0 + m * 16 + g * 4 + r;
        const float v = oacc[m][c4][r] / lrow[m][r];
        attb[((size_t)(b * SQ + qs)) * DM + h * HDIM + c4 * 16 + c16] = f2bf(v);
      }
}

// ---------------- host-side launch ----------------
extern "C" void kernel_launch(void* const* d_in, const int* in_sizes, int n_in,
                              void* d_out, int out_size, void* d_ws, size_t ws_size,
                              hipStream_t stream) {
  const float* x     = (const float*)d_in[0];
  const float* boxes = (const float*)d_in[1];
  const float* Wq    = (const float*)d_in[2];
  const float* bq    = (const float*)d_in[3];
  const float* Wk    = (const float*)d_in[4];
  const float* bk    = (const float*)d_in[5];
  const float* Wv    = (const float*)d_in[6];
  const float* bv    = (const float*)d_in[7];
  const float* Wo    = (const float*)d_in[8];
  const float* bo    = (const float*)d_in[9];
  const float* sb    = (const float*)d_in[10];

  char* ws = (char*)d_ws;
  unsigned short* xb   = (unsigned short*)(ws);             // 6291456 B
  unsigned short* wcat = (unsigned short*)(ws + 6291456);   // 3538944 B
  unsigned short* wob  = (unsigned short*)(ws + 9830400);   // 1179648 B
  unsigned short* qb   = (unsigned short*)(ws + 11010048);  // 6291456 B
  unsigned short* kb   = (unsigned short*)(ws + 17301504);  // 6291456 B
  unsigned short* vtb  = (unsigned short*)(ws + 23592960);  // 6291456 B
  unsigned short* attb = (unsigned short*)(ws + 29884416);  // 6291456 B
  float2* centers      = (float2*)(ws + 36175872);          // 32768 B  (total ~36.2 MB)
  float* out = (float*)d_out;

  prep_kernel<<<14608, 256, 0, stream>>>(x, Wq, Wk, Wv, Wo, boxes, xb, wcat, wob, centers);
  gemm_bt<0><<<32 * 18, 256, 0, stream>>>(xb, wcat, DM, 18, bq, bk, bv, qb, kb, vtb, nullptr);
  attn_kernel<<<384, 256, 0, stream>>>(qb, kb, vtb, centers, sb, attb);
  gemm_bt<1><<<32 * 6, 256, 0, stream>>>(attb, wob, DM, 6, bo, nullptr, nullptr,
                                         nullptr, nullptr, nullptr, out);
}

// Round 3
// 150.392 us; speedup vs baseline: 1.3632x; 1.3632x over previous
//
#include <hip/hip_runtime.h>
#include <stdint.h>

#define NHEADS 12
#define HDIM   64
#define NB     4
#define SQ     1024
#define DM     768
#define NROWS  (NB*SQ)      // 4096
#define NWE    (DM*DM)      // 589824
#define NXE    (NROWS*DM)   // 3145728

typedef __attribute__((ext_vector_type(8))) short short8;
typedef __attribute__((ext_vector_type(4))) float f32x4;

__device__ __forceinline__ unsigned short f2bf(float f) {
  union { float f; unsigned u; } v; v.f = f;
  return (unsigned short)((v.u + 0x7fffu + ((v.u >> 16) & 1u)) >> 16);
}

// pack two fp32 -> two bf16 in a dword (lo = first arg), pure verified ALU
__device__ __forceinline__ unsigned pack2bf(float lo, float hi) {
  return (unsigned)f2bf(lo) | ((unsigned)f2bf(hi) << 16);
}

__device__ __forceinline__ void gload16(const void* g, void* l) {
  __builtin_amdgcn_global_load_lds((__attribute__((address_space(1))) void*)(void*)g,
                                   (__attribute__((address_space(3))) void*)l, 16, 0, 0);
}

// ---------------- prep: fp32 -> bf16 conversions + box centers ----------------
__global__ __launch_bounds__(256) void prep_kernel(
    const float* __restrict__ x, const float* __restrict__ Wq, const float* __restrict__ Wk,
    const float* __restrict__ Wv, const float* __restrict__ Wo, const float* __restrict__ boxes,
    unsigned short* __restrict__ xb, unsigned short* __restrict__ wcat,
    unsigned short* __restrict__ wob, float2* __restrict__ centers) {
  int i = blockIdx.x * 256 + threadIdx.x;
  if (i < NXE) { xb[i] = f2bf(x[i]); return; }
  i -= NXE;
  if (i < NWE) {
    wcat[i]           = f2bf(Wq[i]);
    wcat[NWE + i]     = f2bf(Wk[i]);
    wcat[2 * NWE + i] = f2bf(Wv[i]);
    wob[i]            = f2bf(Wo[i]);
    return;
  }
  i -= NWE;
  if (i < NROWS) {
    float4 bx = ((const float4*)boxes)[i];
    centers[i] = make_float2((bx.x + bx.z) * 0.5f, (bx.y + bx.w) * 0.5f);
  }
}

// ---------------- NT GEMM: C[M,N] = A[M,K] * B[N,K]^T  (bf16 in, fp32 acc) ----
// 128x128 tile, 4 waves (2x2 of 64x64), 16x16x32 bf16 MFMA, global_load_lds.
// EPI=0: QKV epilogue (scatter to Q[bh,s,d]*0.125, K[bh,s,d], Vt[bh,d,s] bf16, +bias)
// EPI=1: fp32 out = acc + b0[n]
template <int EPI>
__global__ __launch_bounds__(256, 2) void gemm_bt(
    const unsigned short* __restrict__ A, const unsigned short* __restrict__ Bw,
    int K, int tiles_n,
    const float* __restrict__ b0, const float* __restrict__ b1, const float* __restrict__ b2,
    unsigned short* __restrict__ outQ, unsigned short* __restrict__ outK,
    unsigned short* __restrict__ outVt, float* __restrict__ outF) {
  __shared__ unsigned short lA[128 * 32];
  __shared__ unsigned short lB[128 * 32];
  const int tid = threadIdx.x, wave = tid >> 6, lane = tid & 63;
  const int tm = blockIdx.x / tiles_n, tn = blockIdx.x % tiles_n;
  const int wr = wave >> 1, wc = wave & 1;
  const int g = lane >> 4, c16 = lane & 15, kb8 = g * 8;

  f32x4 acc[4][4];
#pragma unroll
  for (int m = 0; m < 4; m++)
#pragma unroll
    for (int n = 0; n < 4; n++) acc[m][n] = (f32x4){0.f, 0.f, 0.f, 0.f};

  const unsigned short* Abase = A + (size_t)tm * 128 * K;
  const unsigned short* Bbase = Bw + (size_t)tn * 128 * K;
  const int lin0 = wave * 1024 + lane * 16;
  const int row0 = lin0 >> 6, cb0 = lin0 & 63;
  const int lin1 = lin0 + 4096;
  const int row1 = lin1 >> 6, cb1 = lin1 & 63;

  for (int kt = 0; kt < K; kt += 32) {
    __syncthreads();
    gload16((const char*)(Abase + (size_t)row0 * K + kt) + cb0, (char*)lA + wave * 1024);
    gload16((const char*)(Abase + (size_t)row1 * K + kt) + cb1, (char*)lA + wave * 1024 + 4096);
    gload16((const char*)(Bbase + (size_t)row0 * K + kt) + cb0, (char*)lB + wave * 1024);
    gload16((const char*)(Bbase + (size_t)row1 * K + kt) + cb1, (char*)lB + wave * 1024 + 4096);
    __syncthreads();
    short8 a[4], b[4];
#pragma unroll
    for (int m = 0; m < 4; m++) a[m] = *(const short8*)&lA[(wr * 64 + m * 16 + c16) * 32 + kb8];
#pragma unroll
    for (int n = 0; n < 4; n++) b[n] = *(const short8*)&lB[(wc * 64 + n * 16 + c16) * 32 + kb8];
#pragma unroll
    for (int m = 0; m < 4; m++)
#pragma unroll
      for (int n = 0; n < 4; n++)
        acc[m][n] = __builtin_amdgcn_mfma_f32_16x16x32_bf16(a[m], b[n], acc[m][n], 0, 0, 0);
  }

  // C/D layout (m89): col = lane&15, row = (lane>>4)*4 + r
#pragma unroll
  for (int m = 0; m < 4; m++) {
    const int gm0 = tm * 128 + wr * 64 + m * 16 + g * 4;
    const int bb = gm0 >> 10, ss0 = gm0 & 1023;
#pragma unroll
    for (int n = 0; n < 4; n++) {
      const int gn = tn * 128 + wc * 64 + n * 16 + c16;
      if (EPI == 0) {
        const int which = gn / DM, nn = gn - which * DM;
        const int h = nn >> 6, dh = nn & 63;
        const float bias = (which == 0 ? b0 : which == 1 ? b1 : b2)[nn];
        const float scale = (which == 0) ? 0.125f : 1.0f;  // fold 1/sqrt(Dh) into Q
        if (which == 2) {
          ushort4 pk;
          pk.x = f2bf(acc[m][n][0] + bias);
          pk.y = f2bf(acc[m][n][1] + bias);
          pk.z = f2bf(acc[m][n][2] + bias);
          pk.w = f2bf(acc[m][n][3] + bias);
          *(ushort4*)&outVt[(((size_t)bb * NHEADS + h) * HDIM + dh) * SQ + ss0] = pk;
        } else {
          unsigned short* dst = (which == 0 ? outQ : outK) + ((size_t)bb * NHEADS + h) * SQ * HDIM;
#pragma unroll
          for (int r = 0; r < 4; r++)
            dst[(size_t)(ss0 + r) * HDIM + dh] = f2bf((acc[m][n][r] + bias) * scale);
        }
      } else {
        const float bias = b0[gn];
#pragma unroll
        for (int r = 0; r < 4; r++)
          outF[(size_t)(gm0 + r) * DM + gn] = acc[m][n][r] + bias;
      }
    }
  }
}

// ---------------- fused spatial attention v2 (swapped-operand flash) ----------
// mfma(K,Q): each lane owns ONE q-row (col=lane&15); softmax reduce = in-lane
// tree + 2 shfl_xor. Wave = 16 q-rows x all tokens, KVBLK=64.
// grid: 768 blocks = 48 bh * 16 qtiles (4 waves * 16 rows), XCD-swizzled.
#define PSTR 72  // LDS P stride in shorts
__global__ __launch_bounds__(256, 3) void attn_kernel(
    const unsigned short* __restrict__ Qb, const unsigned short* __restrict__ Kb,
    const unsigned short* __restrict__ Vt, const float2* __restrict__ centers,
    const float* __restrict__ sbias, unsigned short* __restrict__ attb) {
  __shared__ float2 cent_s[SQ];                 // 8 KB
  __shared__ unsigned short plds[4][16 * PSTR]; // 9216 B
  const int tid = threadIdx.x, wave = tid >> 6, lane = tid & 63;
  const int g = lane >> 4, c16 = lane & 15, kb8 = g * 8;
  const int bid = blockIdx.x;
  const int xcd = bid & 7, li = bid >> 3;       // li in 0..95
  const int bh = xcd * 6 + (li >> 4);
  const int qt = li & 15;
  const int b = bh / NHEADS, h = bh - b * NHEADS;
  const float sb = sbias[h];

  const unsigned short* Qh = Qb + (size_t)bh * SQ * HDIM;
  const unsigned short* Kh = Kb + (size_t)bh * SQ * HDIM;
  const unsigned short* Vh = Vt + (size_t)bh * HDIM * SQ;

  for (int i = tid; i < SQ; i += 256) cent_s[i] = centers[b * SQ + i];
  __syncthreads();

  const int q = qt * 64 + wave * 16 + c16;      // this lane's q-row
  short8 qf[2];
  qf[0] = *(const short8*)&Qh[(size_t)q * HDIM + kb8];
  qf[1] = *(const short8*)&Qh[(size_t)q * HDIM + 32 + kb8];
  const float2 cq = cent_s[q];

  float mreg = -1e30f, lreg = 0.f;
  f32x4 oacc[4];
#pragma unroll
  for (int dd = 0; dd < 4; dd++) oacc[dd] = (f32x4){0.f, 0.f, 0.f, 0.f};

  for (int tb = 0; tb < SQ; tb += 64) {
    // --- QK^T swapped: S^T[t, q]; lane holds 16 token-scores for its q-row ---
    f32x4 sv[4];
#pragma unroll
    for (int cc = 0; cc < 4; cc++) {
      short8 k0 = *(const short8*)&Kh[(size_t)(tb + cc * 16 + c16) * HDIM + kb8];
      short8 k1 = *(const short8*)&Kh[(size_t)(tb + cc * 16 + c16) * HDIM + 32 + kb8];
      f32x4 s = (f32x4){0.f, 0.f, 0.f, 0.f};
      s = __builtin_amdgcn_mfma_f32_16x16x32_bf16(k0, qf[0], s, 0, 0, 0);
      s = __builtin_amdgcn_mfma_f32_16x16x32_bf16(k1, qf[1], s, 0, 0, 0);
      sv[cc] = s;
    }
    // --- spatial bias: p = s - dist(cq, ct)*sb  (lane's tokens: cc*16+g*4+r) ---
    float p[4][4];
#pragma unroll
    for (int cc = 0; cc < 4; cc++)
#pragma unroll
      for (int r = 0; r < 4; r++) {
        float2 ct = cent_s[tb + cc * 16 + g * 4 + r];
        float dx = cq.x - ct.x, dy = cq.y - ct.y;
        p[cc][r] = sv[cc][r] - sqrtf(dx * dx + dy * dy) * sb;
      }
    // --- online softmax: in-lane tree + 2 shfl (reduce over g-groups) ---
    float vmax = -1e30f;
#pragma unroll
    for (int cc = 0; cc < 4; cc++) {
      float a0 = fmaxf(p[cc][0], p[cc][1]), a1 = fmaxf(p[cc][2], p[cc][3]);
      vmax = fmaxf(vmax, fmaxf(a0, a1));
    }
    vmax = fmaxf(vmax, __shfl_xor(vmax, 16));
    vmax = fmaxf(vmax, __shfl_xor(vmax, 32));
    const float mn = fmaxf(mreg, vmax);
    const float sc = __expf(mreg - mn);
    float ps = 0.f;
#pragma unroll
    for (int cc = 0; cc < 4; cc++)
#pragma unroll
      for (int r = 0; r < 4; r++) {
        p[cc][r] = __expf(p[cc][r] - mn);
        ps += p[cc][r];
      }
    ps += __shfl_xor(ps, 16);
    ps += __shfl_xor(ps, 32);
    lreg = lreg * sc + ps;
    mreg = mn;
#pragma unroll
    for (int dd = 0; dd < 4; dd++)
#pragma unroll
      for (int r = 0; r < 4; r++) oacc[dd][r] *= sc;
    // --- P -> per-wave LDS [q-row][token] (ALU-packed dword stores) ---
#pragma unroll
    for (int cc = 0; cc < 4; cc++)
#pragma unroll
      for (int i = 0; i < 2; i++)
        *(unsigned*)&plds[wave][c16 * PSTR + cc * 16 + g * 4 + 2 * i] =
            pack2bf(p[cc][2 * i], p[cc][2 * i + 1]);
    // --- PV: O^T[d, q] = mfma(Vt-rows, P-rows) ---
#pragma unroll
    for (int kc = 0; kc < 2; kc++) {
      short8 pf = *(const short8*)&plds[wave][c16 * PSTR + kc * 32 + kb8];
#pragma unroll
      for (int dd = 0; dd < 4; dd++) {
        short8 vf = *(const short8*)&Vh[(size_t)(dd * 16 + c16) * SQ + tb + kc * 32 + kb8];
        oacc[dd] = __builtin_amdgcn_mfma_f32_16x16x32_bf16(vf, pf, oacc[dd], 0, 0, 0);
      }
    }
  }
  // --- epilogue: lane's q-row, d = dd*16 + g*4 + r ---
  const float inv = 1.f / lreg;
#pragma unroll
  for (int dd = 0; dd < 4; dd++) {
    uint2 u;
    u.x = pack2bf(oacc[dd][0] * inv, oacc[dd][1] * inv);
    u.y = pack2bf(oacc[dd][2] * inv, oacc[dd][3] * inv);
    *(uint2*)&attb[(size_t)(b * SQ + q) * DM + h * HDIM + dd * 16 + g * 4] = u;
  }
}

// ---------------- host-side launch ----------------
extern "C" void kernel_launch(void* const* d_in, const int* in_sizes, int n_in,
                              void* d_out, int out_size, void* d_ws, size_t ws_size,
                              hipStream_t stream) {
  const float* x     = (const float*)d_in[0];
  const float* boxes = (const float*)d_in[1];
  const float* Wq    = (const float*)d_in[2];
  const float* bq    = (const float*)d_in[3];
  const float* Wk    = (const float*)d_in[4];
  const float* bk    = (const float*)d_in[5];
  const float* Wv    = (const float*)d_in[6];
  const float* bv    = (const float*)d_in[7];
  const float* Wo    = (const float*)d_in[8];
  const float* bo    = (const float*)d_in[9];
  const float* sb    = (const float*)d_in[10];

  char* ws = (char*)d_ws;
  unsigned short* xb   = (unsigned short*)(ws);             // 6291456 B
  unsigned short* wcat = (unsigned short*)(ws + 6291456);   // 3538944 B
  unsigned short* wob  = (unsigned short*)(ws + 9830400);   // 1179648 B
  unsigned short* qb   = (unsigned short*)(ws + 11010048);  // 6291456 B
  unsigned short* kb   = (unsigned short*)(ws + 17301504);  // 6291456 B
  unsigned short* vtb  = (unsigned short*)(ws + 23592960);  // 6291456 B
  unsigned short* attb = (unsigned short*)(ws + 29884416);  // 6291456 B
  float2* centers      = (float2*)(ws + 36175872);          // 32768 B  (total ~36.2 MB)
  float* out = (float*)d_out;

  prep_kernel<<<14608, 256, 0, stream>>>(x, Wq, Wk, Wv, Wo, boxes, xb, wcat, wob, centers);
  gemm_bt<0><<<32 * 18, 256, 0, stream>>>(xb, wcat, DM, 18, bq, bk, bv, qb, kb, vtb, nullptr);
  attn_kernel<<<768, 256, 0, stream>>>(qb, kb, vtb, centers, sb, attb);
  gemm_bt<1><<<32 * 6, 256, 0, stream>>>(attb, wob, DM, 6, bo, nullptr, nullptr,
                                         nullptr, nullptr, nullptr, out);
}

// Round 4
// 150.170 us; speedup vs baseline: 1.3653x; 1.0015x over previous
//
#include <hip/hip_runtime.h>
#include <stdint.h>

#define NHEADS 12
#define HDIM   64
#define NB     4
#define SQ     1024
#define DM     768
#define NROWS  (NB*SQ)      // 4096
#define NWE    (DM*DM)      // 589824
#define NXE    (NROWS*DM)   // 3145728

typedef __attribute__((ext_vector_type(8))) short short8;
typedef __attribute__((ext_vector_type(4))) float f32x4;

__device__ __forceinline__ unsigned short f2bf(float f) {
  union { float f; unsigned u; } v; v.f = f;
  return (unsigned short)((v.u + 0x7fffu + ((v.u >> 16) & 1u)) >> 16);
}

// pack two fp32 -> two bf16 in a dword (lo = first arg), pure verified ALU
__device__ __forceinline__ unsigned pack2bf(float lo, float hi) {
  return (unsigned)f2bf(lo) | ((unsigned)f2bf(hi) << 16);
}

__device__ __forceinline__ void gload16(const void* g, void* l) {
  __builtin_amdgcn_global_load_lds((__attribute__((address_space(1))) void*)(void*)g,
                                   (__attribute__((address_space(3))) void*)l, 16, 0, 0);
}

// ---------------- prep: fp32 -> bf16 conversions + box centers ----------------
__global__ __launch_bounds__(256) void prep_kernel(
    const float* __restrict__ x, const float* __restrict__ Wq, const float* __restrict__ Wk,
    const float* __restrict__ Wv, const float* __restrict__ Wo, const float* __restrict__ boxes,
    unsigned short* __restrict__ xb, unsigned short* __restrict__ wcat,
    unsigned short* __restrict__ wob, float2* __restrict__ centers) {
  int i = blockIdx.x * 256 + threadIdx.x;
  if (i < NXE) { xb[i] = f2bf(x[i]); return; }
  i -= NXE;
  if (i < NWE) {
    wcat[i]           = f2bf(Wq[i]);
    wcat[NWE + i]     = f2bf(Wk[i]);
    wcat[2 * NWE + i] = f2bf(Wv[i]);
    wob[i]            = f2bf(Wo[i]);
    return;
  }
  i -= NWE;
  if (i < NROWS) {
    float4 bx = ((const float4*)boxes)[i];
    centers[i] = make_float2((bx.x + bx.z) * 0.5f, (bx.y + bx.w) * 0.5f);
  }
}

// ---------------- NT GEMM: C[M,N] = A[M,K] * B[N,K]^T  (bf16 in, fp32 acc) ----
// 128x128 tile, 4 waves (2x2 of 64x64), 16x16x32 bf16 MFMA, global_load_lds.
// EPI=0: QKV epilogue (Q scaled by 0.125*log2e for exp2-domain softmax)
// EPI=1: fp32 out = acc + b0[n]
template <int EPI>
__global__ __launch_bounds__(256, 2) void gemm_bt(
    const unsigned short* __restrict__ A, const unsigned short* __restrict__ Bw,
    int K, int tiles_n,
    const float* __restrict__ b0, const float* __restrict__ b1, const float* __restrict__ b2,
    unsigned short* __restrict__ outQ, unsigned short* __restrict__ outK,
    unsigned short* __restrict__ outVt, float* __restrict__ outF) {
  __shared__ unsigned short lA[128 * 32];
  __shared__ unsigned short lB[128 * 32];
  const int tid = threadIdx.x, wave = tid >> 6, lane = tid & 63;
  const int tm = blockIdx.x / tiles_n, tn = blockIdx.x % tiles_n;
  const int wr = wave >> 1, wc = wave & 1;
  const int g = lane >> 4, c16 = lane & 15, kb8 = g * 8;

  f32x4 acc[4][4];
#pragma unroll
  for (int m = 0; m < 4; m++)
#pragma unroll
    for (int n = 0; n < 4; n++) acc[m][n] = (f32x4){0.f, 0.f, 0.f, 0.f};

  const unsigned short* Abase = A + (size_t)tm * 128 * K;
  const unsigned short* Bbase = Bw + (size_t)tn * 128 * K;
  const int lin0 = wave * 1024 + lane * 16;
  const int row0 = lin0 >> 6, cb0 = lin0 & 63;
  const int lin1 = lin0 + 4096;
  const int row1 = lin1 >> 6, cb1 = lin1 & 63;

  for (int kt = 0; kt < K; kt += 32) {
    __syncthreads();
    gload16((const char*)(Abase + (size_t)row0 * K + kt) + cb0, (char*)lA + wave * 1024);
    gload16((const char*)(Abase + (size_t)row1 * K + kt) + cb1, (char*)lA + wave * 1024 + 4096);
    gload16((const char*)(Bbase + (size_t)row0 * K + kt) + cb0, (char*)lB + wave * 1024);
    gload16((const char*)(Bbase + (size_t)row1 * K + kt) + cb1, (char*)lB + wave * 1024 + 4096);
    __syncthreads();
    short8 a[4], b[4];
#pragma unroll
    for (int m = 0; m < 4; m++) a[m] = *(const short8*)&lA[(wr * 64 + m * 16 + c16) * 32 + kb8];
#pragma unroll
    for (int n = 0; n < 4; n++) b[n] = *(const short8*)&lB[(wc * 64 + n * 16 + c16) * 32 + kb8];
#pragma unroll
    for (int m = 0; m < 4; m++)
#pragma unroll
      for (int n = 0; n < 4; n++)
        acc[m][n] = __builtin_amdgcn_mfma_f32_16x16x32_bf16(a[m], b[n], acc[m][n], 0, 0, 0);
  }

  // C/D layout (m89): col = lane&15, row = (lane>>4)*4 + r
#pragma unroll
  for (int m = 0; m < 4; m++) {
    const int gm0 = tm * 128 + wr * 64 + m * 16 + g * 4;
    const int bb = gm0 >> 10, ss0 = gm0 & 1023;
#pragma unroll
    for (int n = 0; n < 4; n++) {
      const int gn = tn * 128 + wc * 64 + n * 16 + c16;
      if (EPI == 0) {
        const int which = gn / DM, nn = gn - which * DM;
        const int h = nn >> 6, dh = nn & 63;
        const float bias = (which == 0 ? b0 : which == 1 ? b1 : b2)[nn];
        // fold 1/sqrt(Dh) * log2(e) into Q (exp2-domain softmax)
        const float scale = (which == 0) ? 0.1803368801f : 1.0f;
        if (which == 2) {
          ushort4 pk;
          pk.x = f2bf(acc[m][n][0] + bias);
          pk.y = f2bf(acc[m][n][1] + bias);
          pk.z = f2bf(acc[m][n][2] + bias);
          pk.w = f2bf(acc[m][n][3] + bias);
          *(ushort4*)&outVt[(((size_t)bb * NHEADS + h) * HDIM + dh) * SQ + ss0] = pk;
        } else {
          unsigned short* dst = (which == 0 ? outQ : outK) + ((size_t)bb * NHEADS + h) * SQ * HDIM;
#pragma unroll
          for (int r = 0; r < 4; r++)
            dst[(size_t)(ss0 + r) * HDIM + dh] = f2bf((acc[m][n][r] + bias) * scale);
        }
      } else {
        const float bias = b0[gn];
#pragma unroll
        for (int r = 0; r < 4; r++)
          outF[(size_t)(gm0 + r) * DM + gn] = acc[m][n][r] + bias;
      }
    }
  }
}

// ---------------- fused spatial attention v3 (swapped-operand flash) ----------
// mfma(K,Q): each lane owns ONE q-row (col=lane&15); softmax in exp2 domain,
// reduce = in-lane tree + 2 shfl_xor. KVBLK=128, 8 loop trips.
// grid: 768 blocks = 48 bh * 16 qtiles (4 waves * 16 rows), XCD-swizzled.
#define KVB  128
#define PSTR 136  // LDS P row stride in shorts (128 + 8 pad)
__global__ __launch_bounds__(256, 3) void attn_kernel(
    const unsigned short* __restrict__ Qb, const unsigned short* __restrict__ Kb,
    const unsigned short* __restrict__ Vt, const float2* __restrict__ centers,
    const float* __restrict__ sbias, unsigned short* __restrict__ attb) {
  __shared__ float2 cent_s[SQ];                 // 8 KB
  __shared__ unsigned short plds[4][16 * PSTR]; // 17408 B
  const int tid = threadIdx.x, wave = tid >> 6, lane = tid & 63;
  const int g = lane >> 4, c16 = lane & 15, kb8 = g * 8;
  const int bid = blockIdx.x;
  const int xcd = bid & 7, li = bid >> 3;       // li in 0..95
  const int bh = xcd * 6 + (li >> 4);
  const int qt = li & 15;
  const int b = bh / NHEADS, h = bh - b * NHEADS;
  const float sb = sbias[h] * 1.44269504f;      // exp2-domain bias coefficient

  const unsigned short* Qh = Qb + (size_t)bh * SQ * HDIM;
  const unsigned short* Kh = Kb + (size_t)bh * SQ * HDIM;
  const unsigned short* Vh = Vt + (size_t)bh * HDIM * SQ;

  for (int i = tid; i < SQ; i += 256) cent_s[i] = centers[b * SQ + i];
  __syncthreads();

  const int q = qt * 64 + wave * 16 + c16;      // this lane's q-row
  short8 qf[2];
  qf[0] = *(const short8*)&Qh[(size_t)q * HDIM + kb8];
  qf[1] = *(const short8*)&Qh[(size_t)q * HDIM + 32 + kb8];
  const float2 cq = cent_s[q];

  float mreg = -1e30f, lreg = 0.f;
  f32x4 oacc[4];
#pragma unroll
  for (int dd = 0; dd < 4; dd++) oacc[dd] = (f32x4){0.f, 0.f, 0.f, 0.f};

  for (int tb = 0; tb < SQ; tb += KVB) {
    // --- QK^T swapped: lane holds 32 token-scores for its q-row ---
    f32x4 sv[8];
#pragma unroll
    for (int cc = 0; cc < 8; cc++) {
      short8 k0 = *(const short8*)&Kh[(size_t)(tb + cc * 16 + c16) * HDIM + kb8];
      short8 k1 = *(const short8*)&Kh[(size_t)(tb + cc * 16 + c16) * HDIM + 32 + kb8];
      f32x4 s = (f32x4){0.f, 0.f, 0.f, 0.f};
      s = __builtin_amdgcn_mfma_f32_16x16x32_bf16(k0, qf[0], s, 0, 0, 0);
      s = __builtin_amdgcn_mfma_f32_16x16x32_bf16(k1, qf[1], s, 0, 0, 0);
      sv[cc] = s;
    }
    // --- spatial bias in place: sv -= dist(cq, ct)*sb (raw v_sqrt) ---
#pragma unroll
    for (int cc = 0; cc < 8; cc++)
#pragma unroll
      for (int r = 0; r < 4; r++) {
        float2 ct = cent_s[tb + cc * 16 + g * 4 + r];
        float dx = cq.x - ct.x, dy = cq.y - ct.y;
        sv[cc][r] -= __builtin_amdgcn_sqrtf(dx * dx + dy * dy) * sb;
      }
    // --- online softmax (exp2 domain): in-lane tree + 2 shfl ---
    float vmax = -1e30f;
#pragma unroll
    for (int cc = 0; cc < 8; cc++) {
      float a0 = fmaxf(sv[cc][0], sv[cc][1]), a1 = fmaxf(sv[cc][2], sv[cc][3]);
      vmax = fmaxf(vmax, fmaxf(a0, a1));
    }
    vmax = fmaxf(vmax, __shfl_xor(vmax, 16));
    vmax = fmaxf(vmax, __shfl_xor(vmax, 32));
    const float mn = fmaxf(mreg, vmax);
    const float sc = __builtin_amdgcn_exp2f(mreg - mn);
    float ps = 0.f;
#pragma unroll
    for (int cc = 0; cc < 8; cc++)
#pragma unroll
      for (int r = 0; r < 4; r++) {
        sv[cc][r] = __builtin_amdgcn_exp2f(sv[cc][r] - mn);
        ps += sv[cc][r];
      }
    ps += __shfl_xor(ps, 16);
    ps += __shfl_xor(ps, 32);
    lreg = lreg * sc + ps;
    mreg = mn;
#pragma unroll
    for (int dd = 0; dd < 4; dd++)
#pragma unroll
      for (int r = 0; r < 4; r++) oacc[dd][r] *= sc;
    // --- P -> per-wave LDS [q-row][token] (b64 packed stores) ---
#pragma unroll
    for (int cc = 0; cc < 8; cc++) {
      uint2 u;
      u.x = pack2bf(sv[cc][0], sv[cc][1]);
      u.y = pack2bf(sv[cc][2], sv[cc][3]);
      *(uint2*)&plds[wave][c16 * PSTR + cc * 16 + g * 4] = u;
    }
    // --- PV: O^T[d, q] = mfma(Vt-rows, P-rows), kc-loop caps live VGPRs ---
#pragma unroll
    for (int kc = 0; kc < 4; kc++) {
      short8 pf = *(const short8*)&plds[wave][c16 * PSTR + kc * 32 + kb8];
#pragma unroll
      for (int dd = 0; dd < 4; dd++) {
        short8 vf = *(const short8*)&Vh[(size_t)(dd * 16 + c16) * SQ + tb + kc * 32 + kb8];
        oacc[dd] = __builtin_amdgcn_mfma_f32_16x16x32_bf16(vf, pf, oacc[dd], 0, 0, 0);
      }
    }
  }
  // --- epilogue: lane's q-row, d = dd*16 + g*4 + r ---
  const float inv = 1.f / lreg;
#pragma unroll
  for (int dd = 0; dd < 4; dd++) {
    uint2 u;
    u.x = pack2bf(oacc[dd][0] * inv, oacc[dd][1] * inv);
    u.y = pack2bf(oacc[dd][2] * inv, oacc[dd][3] * inv);
    *(uint2*)&attb[(size_t)(b * SQ + q) * DM + h * HDIM + dd * 16 + g * 4] = u;
  }
}

// ---------------- host-side launch ----------------
extern "C" void kernel_launch(void* const* d_in, const int* in_sizes, int n_in,
                              void* d_out, int out_size, void* d_ws, size_t ws_size,
                              hipStream_t stream) {
  const float* x     = (const float*)d_in[0];
  const float* boxes = (const float*)d_in[1];
  const float* Wq    = (const float*)d_in[2];
  const float* bq    = (const float*)d_in[3];
  const float* Wk    = (const float*)d_in[4];
  const float* bk    = (const float*)d_in[5];
  const float* Wv    = (const float*)d_in[6];
  const float* bv    = (const float*)d_in[7];
  const float* Wo    = (const float*)d_in[8];
  const float* bo    = (const float*)d_in[9];
  const float* sb    = (const float*)d_in[10];

  char* ws = (char*)d_ws;
  unsigned short* xb   = (unsigned short*)(ws);             // 6291456 B
  unsigned short* wcat = (unsigned short*)(ws + 6291456);   // 3538944 B
  unsigned short* wob  = (unsigned short*)(ws + 9830400);   // 1179648 B
  unsigned short* qb   = (unsigned short*)(ws + 11010048);  // 6291456 B
  unsigned short* kb   = (unsigned short*)(ws + 17301504);  // 6291456 B
  unsigned short* vtb  = (unsigned short*)(ws + 23592960);  // 6291456 B
  unsigned short* attb = (unsigned short*)(ws + 29884416);  // 6291456 B
  float2* centers      = (float2*)(ws + 36175872);          // 32768 B  (total ~36.2 MB)
  float* out = (float*)d_out;

  prep_kernel<<<14608, 256, 0, stream>>>(x, Wq, Wk, Wv, Wo, boxes, xb, wcat, wob, centers);
  gemm_bt<0><<<32 * 18, 256, 0, stream>>>(xb, wcat, DM, 18, bq, bk, bv, qb, kb, vtb, nullptr);
  attn_kernel<<<768, 256, 0, stream>>>(qb, kb, vtb, centers, sb, attb);
  gemm_bt<1><<<32 * 6, 256, 0, stream>>>(attb, wob, DM, 6, bo, nullptr, nullptr,
                                         nullptr, nullptr, nullptr, out);
}

// Round 5
// 150.138 us; speedup vs baseline: 1.3656x; 1.0002x over previous
//
#include <hip/hip_runtime.h>
#include <stdint.h>

#define NHEADS 12
#define HDIM   64
#define NB     4
#define SQ     1024
#define DM     768
#define NROWS  (NB*SQ)      // 4096
#define NWE    (DM*DM)      // 589824
#define NXE    (NROWS*DM)   // 3145728

typedef __attribute__((ext_vector_type(8))) short short8;
typedef __attribute__((ext_vector_type(4))) float f32x4;

__device__ __forceinline__ unsigned short f2bf(float f) {
  union { float f; unsigned u; } v; v.f = f;
  return (unsigned short)((v.u + 0x7fffu + ((v.u >> 16) & 1u)) >> 16);
}

// pack two fp32 -> two bf16 in a dword (lo = first arg), pure verified ALU
__device__ __forceinline__ unsigned pack2bf(float lo, float hi) {
  return (unsigned)f2bf(lo) | ((unsigned)f2bf(hi) << 16);
}

__device__ __forceinline__ void gload16(const void* g, void* l) {
  __builtin_amdgcn_global_load_lds((__attribute__((address_space(1))) void*)(void*)g,
                                   (__attribute__((address_space(3))) void*)l, 16, 0, 0);
}

// ---------------- prep: fp32 -> bf16 conversions + box centers ----------------
__global__ __launch_bounds__(256) void prep_kernel(
    const float* __restrict__ x, const float* __restrict__ Wq, const float* __restrict__ Wk,
    const float* __restrict__ Wv, const float* __restrict__ Wo, const float* __restrict__ boxes,
    unsigned short* __restrict__ xb, unsigned short* __restrict__ wcat,
    unsigned short* __restrict__ wob, float2* __restrict__ centers) {
  int i = blockIdx.x * 256 + threadIdx.x;
  if (i < NXE) { xb[i] = f2bf(x[i]); return; }
  i -= NXE;
  if (i < NWE) {
    wcat[i]           = f2bf(Wq[i]);
    wcat[NWE + i]     = f2bf(Wk[i]);
    wcat[2 * NWE + i] = f2bf(Wv[i]);
    wob[i]            = f2bf(Wo[i]);
    return;
  }
  i -= NWE;
  if (i < NROWS) {
    float4 bx = ((const float4*)boxes)[i];
    centers[i] = make_float2((bx.x + bx.z) * 0.5f, (bx.y + bx.w) * 0.5f);
  }
}

// ---------------- NT GEMM: C[M,N] = A[M,K] * B[N,K]^T  (bf16 in, fp32 acc) ----
// 128x128 tile, 4 waves (2x2 of 64x64), 16x16x32 bf16 MFMA, global_load_lds.
// EPI=0: QKV epilogue (Q scaled by 0.125*log2e for exp2-domain softmax)
// EPI=1: fp32 out = acc + b0[n]
template <int EPI>
__global__ __launch_bounds__(256, 2) void gemm_bt(
    const unsigned short* __restrict__ A, const unsigned short* __restrict__ Bw,
    int K, int tiles_n,
    const float* __restrict__ b0, const float* __restrict__ b1, const float* __restrict__ b2,
    unsigned short* __restrict__ outQ, unsigned short* __restrict__ outK,
    unsigned short* __restrict__ outVt, float* __restrict__ outF) {
  __shared__ unsigned short lA[128 * 32];
  __shared__ unsigned short lB[128 * 32];
  const int tid = threadIdx.x, wave = tid >> 6, lane = tid & 63;
  const int tm = blockIdx.x / tiles_n, tn = blockIdx.x % tiles_n;
  const int wr = wave >> 1, wc = wave & 1;
  const int g = lane >> 4, c16 = lane & 15, kb8 = g * 8;

  f32x4 acc[4][4];
#pragma unroll
  for (int m = 0; m < 4; m++)
#pragma unroll
    for (int n = 0; n < 4; n++) acc[m][n] = (f32x4){0.f, 0.f, 0.f, 0.f};

  const unsigned short* Abase = A + (size_t)tm * 128 * K;
  const unsigned short* Bbase = Bw + (size_t)tn * 128 * K;
  const int lin0 = wave * 1024 + lane * 16;
  const int row0 = lin0 >> 6, cb0 = lin0 & 63;
  const int lin1 = lin0 + 4096;
  const int row1 = lin1 >> 6, cb1 = lin1 & 63;

  for (int kt = 0; kt < K; kt += 32) {
    __syncthreads();
    gload16((const char*)(Abase + (size_t)row0 * K + kt) + cb0, (char*)lA + wave * 1024);
    gload16((const char*)(Abase + (size_t)row1 * K + kt) + cb1, (char*)lA + wave * 1024 + 4096);
    gload16((const char*)(Bbase + (size_t)row0 * K + kt) + cb0, (char*)lB + wave * 1024);
    gload16((const char*)(Bbase + (size_t)row1 * K + kt) + cb1, (char*)lB + wave * 1024 + 4096);
    __syncthreads();
    short8 a[4], b[4];
#pragma unroll
    for (int m = 0; m < 4; m++) a[m] = *(const short8*)&lA[(wr * 64 + m * 16 + c16) * 32 + kb8];
#pragma unroll
    for (int n = 0; n < 4; n++) b[n] = *(const short8*)&lB[(wc * 64 + n * 16 + c16) * 32 + kb8];
#pragma unroll
    for (int m = 0; m < 4; m++)
#pragma unroll
      for (int n = 0; n < 4; n++)
        acc[m][n] = __builtin_amdgcn_mfma_f32_16x16x32_bf16(a[m], b[n], acc[m][n], 0, 0, 0);
  }

  // C/D layout (m89): col = lane&15, row = (lane>>4)*4 + r
#pragma unroll
  for (int m = 0; m < 4; m++) {
    const int gm0 = tm * 128 + wr * 64 + m * 16 + g * 4;
    const int bb = gm0 >> 10, ss0 = gm0 & 1023;
#pragma unroll
    for (int n = 0; n < 4; n++) {
      const int gn = tn * 128 + wc * 64 + n * 16 + c16;
      if (EPI == 0) {
        const int which = gn / DM, nn = gn - which * DM;
        const int h = nn >> 6, dh = nn & 63;
        const float bias = (which == 0 ? b0 : which == 1 ? b1 : b2)[nn];
        // fold 1/sqrt(Dh) * log2(e) into Q (exp2-domain softmax)
        const float scale = (which == 0) ? 0.1803368801f : 1.0f;
        if (which == 2) {
          ushort4 pk;
          pk.x = f2bf(acc[m][n][0] + bias);
          pk.y = f2bf(acc[m][n][1] + bias);
          pk.z = f2bf(acc[m][n][2] + bias);
          pk.w = f2bf(acc[m][n][3] + bias);
          *(ushort4*)&outVt[(((size_t)bb * NHEADS + h) * HDIM + dh) * SQ + ss0] = pk;
        } else {
          unsigned short* dst = (which == 0 ? outQ : outK) + ((size_t)bb * NHEADS + h) * SQ * HDIM;
#pragma unroll
          for (int r = 0; r < 4; r++)
            dst[(size_t)(ss0 + r) * HDIM + dh] = f2bf((acc[m][n][r] + bias) * scale);
        }
      } else {
        const float bias = b0[gn];
#pragma unroll
        for (int r = 0; r < 4; r++)
          outF[(size_t)(gm0 + r) * DM + gn] = acc[m][n][r] + bias;
      }
    }
  }
}

// ---------------- fused spatial attention v4 (prefetched, defer-max) ---------
// Swapped-operand flash: lane owns one q-row. K prefetched across iterations,
// V staged in regs, defer-max removes all in-loop shfls (l reduced at exit).
#define KVB  128
#define PSTR 136  // LDS P row stride in shorts (128 + 8 pad)
__global__ __launch_bounds__(256, 3) void attn_kernel(
    const unsigned short* __restrict__ Qb, const unsigned short* __restrict__ Kb,
    const unsigned short* __restrict__ Vt, const float2* __restrict__ centers,
    const float* __restrict__ sbias, unsigned short* __restrict__ attb) {
  __shared__ float2 cent_s[SQ];                 // 8 KB
  __shared__ unsigned short plds[4][16 * PSTR]; // 17408 B
  const int tid = threadIdx.x, wave = tid >> 6, lane = tid & 63;
  const int g = lane >> 4, c16 = lane & 15, kb8 = g * 8;
  const int bid = blockIdx.x;
  const int xcd = bid & 7, li = bid >> 3;       // li in 0..95
  const int bh = xcd * 6 + (li >> 4);
  const int qt = li & 15;
  const int b = bh / NHEADS, h = bh - b * NHEADS;
  const float sb = sbias[h] * 1.44269504f;      // exp2-domain bias coefficient

  const unsigned short* Qh = Qb + (size_t)bh * SQ * HDIM;
  const unsigned short* Kh = Kb + (size_t)bh * SQ * HDIM;
  const unsigned short* Vh = Vt + (size_t)bh * HDIM * SQ;

  for (int i = tid; i < SQ; i += 256) cent_s[i] = centers[b * SQ + i];
  __syncthreads();

  const int q = qt * 64 + wave * 16 + c16;      // this lane's q-row
  short8 qf[2];
  qf[0] = *(const short8*)&Qh[(size_t)q * HDIM + kb8];
  qf[1] = *(const short8*)&Qh[(size_t)q * HDIM + 32 + kb8];
  const float2 cq = cent_s[q];

  float mreg = -1e30f, lreg = 0.f;              // lreg: per-lane partial sum
  f32x4 oacc[4];
#pragma unroll
  for (int dd = 0; dd < 4; dd++) oacc[dd] = (f32x4){0.f, 0.f, 0.f, 0.f};

  // prologue: prefetch K tile 0
  short8 kst[16];
#pragma unroll
  for (int cc = 0; cc < 8; cc++) {
    kst[2 * cc]     = *(const short8*)&Kh[(size_t)(cc * 16 + c16) * HDIM + kb8];
    kst[2 * cc + 1] = *(const short8*)&Kh[(size_t)(cc * 16 + c16) * HDIM + 32 + kb8];
  }

#pragma unroll 1
  for (int tb = 0; tb < SQ; tb += KVB) {
    // --- 1. QK^T from prefetched kst (kst dead after) ---
    f32x4 sv[8];
#pragma unroll
    for (int cc = 0; cc < 8; cc++) {
      f32x4 s = (f32x4){0.f, 0.f, 0.f, 0.f};
      s = __builtin_amdgcn_mfma_f32_16x16x32_bf16(kst[2 * cc], qf[0], s, 0, 0, 0);
      s = __builtin_amdgcn_mfma_f32_16x16x32_bf16(kst[2 * cc + 1], qf[1], s, 0, 0, 0);
      sv[cc] = s;
    }
    // --- 2. spatial bias (vectorized cent_s reads, raw v_sqrt) ---
#pragma unroll
    for (int cc = 0; cc < 8; cc++) {
      const float4* cp = (const float4*)&cent_s[tb + cc * 16 + g * 4];
      float4 c01 = cp[0], c23 = cp[1];
      float dx, dy;
      dx = cq.x - c01.x; dy = cq.y - c01.y;
      sv[cc][0] -= __builtin_amdgcn_sqrtf(dx * dx + dy * dy) * sb;
      dx = cq.x - c01.z; dy = cq.y - c01.w;
      sv[cc][1] -= __builtin_amdgcn_sqrtf(dx * dx + dy * dy) * sb;
      dx = cq.x - c23.x; dy = cq.y - c23.y;
      sv[cc][2] -= __builtin_amdgcn_sqrtf(dx * dx + dy * dy) * sb;
      dx = cq.x - c23.z; dy = cq.y - c23.w;
      sv[cc][3] -= __builtin_amdgcn_sqrtf(dx * dx + dy * dy) * sb;
    }
    // --- 3. stage V tile in regs (covered by softmax+pack below) ---
    short8 vst[16];
#pragma unroll
    for (int kc = 0; kc < 4; kc++)
#pragma unroll
      for (int dd = 0; dd < 4; dd++)
        vst[kc * 4 + dd] =
            *(const short8*)&Vh[(size_t)(dd * 16 + c16) * SQ + tb + kc * 32 + kb8];
    // --- 4. defer-max online softmax (no shfl in common path) ---
    float lm = -1e30f;
#pragma unroll
    for (int cc = 0; cc < 8; cc++) {
      float a0 = fmaxf(sv[cc][0], sv[cc][1]), a1 = fmaxf(sv[cc][2], sv[cc][3]);
      lm = fmaxf(lm, fmaxf(a0, a1));
    }
    if (!__all(lm <= mreg + 8.0f)) {
      float vmax = fmaxf(lm, __shfl_xor(lm, 16));
      vmax = fmaxf(vmax, __shfl_xor(vmax, 32));
      const float mn = fmaxf(mreg, vmax);
      const float sc = __builtin_amdgcn_exp2f(mreg - mn);
      lreg *= sc;
#pragma unroll
      for (int dd = 0; dd < 4; dd++)
#pragma unroll
        for (int r = 0; r < 4; r++) oacc[dd][r] *= sc;
      mreg = mn;
    }
    float ps = 0.f;
#pragma unroll
    for (int cc = 0; cc < 8; cc++)
#pragma unroll
      for (int r = 0; r < 4; r++) {
        sv[cc][r] = __builtin_amdgcn_exp2f(sv[cc][r] - mreg);
        ps += sv[cc][r];
      }
    lreg += ps;
    // --- 5. P -> per-wave LDS [q-row][token] ---
#pragma unroll
    for (int cc = 0; cc < 8; cc++) {
      uint2 u;
      u.x = pack2bf(sv[cc][0], sv[cc][1]);
      u.y = pack2bf(sv[cc][2], sv[cc][3]);
      *(uint2*)&plds[wave][c16 * PSTR + cc * 16 + g * 4] = u;
    }
    // --- 6. prefetch K for next tile (covered by PV) ---
    const int tn = (tb + KVB) & (SQ - 1);
#pragma unroll
    for (int cc = 0; cc < 8; cc++) {
      kst[2 * cc]     = *(const short8*)&Kh[(size_t)(tn + cc * 16 + c16) * HDIM + kb8];
      kst[2 * cc + 1] = *(const short8*)&Kh[(size_t)(tn + cc * 16 + c16) * HDIM + 32 + kb8];
    }
    // --- 7. PV: O^T[d,q] = mfma(V-rows, P-rows) ---
#pragma unroll
    for (int kc = 0; kc < 4; kc++) {
      short8 pf = *(const short8*)&plds[wave][c16 * PSTR + kc * 32 + kb8];
#pragma unroll
      for (int dd = 0; dd < 4; dd++)
        oacc[dd] = __builtin_amdgcn_mfma_f32_16x16x32_bf16(vst[kc * 4 + dd], pf, oacc[dd], 0, 0, 0);
    }
  }
  // --- epilogue: reduce l across the 4 row-group lanes, write O ---
  lreg += __shfl_xor(lreg, 16);
  lreg += __shfl_xor(lreg, 32);
  const float inv = 1.f / lreg;
#pragma unroll
  for (int dd = 0; dd < 4; dd++) {
    uint2 u;
    u.x = pack2bf(oacc[dd][0] * inv, oacc[dd][1] * inv);
    u.y = pack2bf(oacc[dd][2] * inv, oacc[dd][3] * inv);
    *(uint2*)&attb[(size_t)(b * SQ + q) * DM + h * HDIM + dd * 16 + g * 4] = u;
  }
}

// ---------------- host-side launch ----------------
extern "C" void kernel_launch(void* const* d_in, const int* in_sizes, int n_in,
                              void* d_out, int out_size, void* d_ws, size_t ws_size,
                              hipStream_t stream) {
  const float* x     = (const float*)d_in[0];
  const float* boxes = (const float*)d_in[1];
  const float* Wq    = (const float*)d_in[2];
  const float* bq    = (const float*)d_in[3];
  const float* Wk    = (const float*)d_in[4];
  const float* bk    = (const float*)d_in[5];
  const float* Wv    = (const float*)d_in[6];
  const float* bv    = (const float*)d_in[7];
  const float* Wo    = (const float*)d_in[8];
  const float* bo    = (const float*)d_in[9];
  const float* sb    = (const float*)d_in[10];

  char* ws = (char*)d_ws;
  unsigned short* xb   = (unsigned short*)(ws);             // 6291456 B
  unsigned short* wcat = (unsigned short*)(ws + 6291456);   // 3538944 B
  unsigned short* wob  = (unsigned short*)(ws + 9830400);   // 1179648 B
  unsigned short* qb   = (unsigned short*)(ws + 11010048);  // 6291456 B
  unsigned short* kb   = (unsigned short*)(ws + 17301504);  // 6291456 B
  unsigned short* vtb  = (unsigned short*)(ws + 23592960);  // 6291456 B
  unsigned short* attb = (unsigned short*)(ws + 29884416);  // 6291456 B
  float2* centers      = (float2*)(ws + 36175872);          // 32768 B  (total ~36.2 MB)
  float* out = (float*)d_out;

  prep_kernel<<<14608, 256, 0, stream>>>(x, Wq, Wk, Wv, Wo, boxes, xb, wcat, wob, centers);
  gemm_bt<0><<<32 * 18, 256, 0, stream>>>(xb, wcat, DM, 18, bq, bk, bv, qb, kb, vtb, nullptr);
  attn_kernel<<<768, 256, 0, stream>>>(qb, kb, vtb, centers, sb, attb);
  gemm_bt<1><<<32 * 6, 256, 0, stream>>>(attb, wob, DM, 6, bo, nullptr, nullptr,
                                         nullptr, nullptr, nullptr, out);
}